// Round 8
// baseline (146832.861 us; speedup 1.0000x reference)
//
#include <hip/hip_runtime.h>
#include <math.h>

#define Tn   16384
#define Mg   200
#define Nc   6
#define TOT  1200
#define Kk   25
#define Din  784
#define CH   32                 // Za/Y chunk length (steps)

// ---------------------------------------------------------------- transpose
__global__ void transpose_k(const float* __restrict__ src, float* __restrict__ dst,
                            int R, int C) {
    __shared__ float tile[32][33];
    int bx = blockIdx.x * 32, by = blockIdx.y * 32;
    int x = bx + threadIdx.x;
    for (int j = 0; j < 32; j += 8) {
        int y = by + threadIdx.y + j;
        if (x < C && y < R) tile[threadIdx.y + j][threadIdx.x] = src[(size_t)y * C + x];
    }
    __syncthreads();
    int x2 = by + threadIdx.x;
    for (int j = 0; j < 32; j += 8) {
        int y2 = bx + threadIdx.y + j;
        if (x2 < R && y2 < C) dst[(size_t)y2 * R + x2] = tile[threadIdx.x][threadIdx.y + j];
    }
}

// ------------------------------------------------- Za = X @ Wa^T + ba  (16384 x 200)
__global__ void za_k(const float* __restrict__ X, const float* __restrict__ Wa,
                     const float* __restrict__ ba, float* __restrict__ Za) {
    __shared__ float xs[16][788];
    const int tid = threadIdx.x;
    const int t0  = blockIdx.x * 16;
    for (int idx = tid; idx < 16 * Din; idx += 256) {
        int tt = idx / Din, kk = idx - tt * Din;
        xs[tt][kk] = X[(size_t)(t0 + tt) * Din + kk];
    }
    __syncthreads();
    const int tq = tid & 15, gq = tid >> 4;
    const float4* xrow = reinterpret_cast<const float4*>(&xs[tq][0]);
    for (int g = gq; g < Mg; g += 16) {
        float acc = ba[g];
        const float4* wrow = reinterpret_cast<const float4*>(Wa + (size_t)g * Din);
        for (int k4 = 0; k4 < Din / 4; ++k4) {
            float4 a = xrow[k4], b = wrow[k4];
            acc = fmaf(a.x, b.x, acc); acc = fmaf(a.y, b.y, acc);
            acc = fmaf(a.z, b.z, acc); acc = fmaf(a.w, b.w, acc);
        }
        Za[(size_t)(t0 + tq) * Mg + g] = acc;
    }
}

// ------------------------------------------------------------- serial recurrence
// ABLATION TEMPLATE. V=0: full (real outputs). V=1: no rank scan. V=2: no gather.
// V=3: no min/shfl/argmax. V=4: no barriers (scratch-quality data, offsets clamped).
// V=5: no tanh. Variants 1-5 run 4096 steps into YP/outTail which V0 (launched
// last, 16384 steps) fully overwrites -> d_out exact.
template<int V>
__launch_bounds__(256, 1)
__global__ void serial_t(const float* __restrict__ Za, const float* __restrict__ WbT,
                         const float* __restrict__ bb,
                         unsigned long long* __restrict__ YP,
                         float* __restrict__ outTail, int nsteps) {
    __shared__ alignas(16) unsigned long long lamk[Mg];
    __shared__ alignas(16) unsigned long long sel[26];
    __shared__ alignas(16) float red[4];
    __shared__ alignas(16) float zs[CH * Mg];
    __shared__ alignas(16) unsigned long long ypk[CH * Kk];

    const int tid = threadIdx.x;
    const bool own = (tid < Mg);
    const int b = Nc * tid;

    float u0=0.f,u1=0.f,u2=0.f,u3=0.f,u4=0.f,u5=0.f;
    float p0=0.f,p1=0.f,p2=0.f,p3=0.f,p4=0.f,p5=0.f;
    float b0=0.f,b1=0.f,b2=0.f,b3=0.f,b4=0.f,b5=0.f;
    float alpha = 0.f;
    if (own) {
        b0=bb[b]; b1=bb[b+1]; b2=bb[b+2]; b3=bb[b+3]; b4=bb[b+4]; b5=bb[b+5];
    }
    if (tid < 26) sel[tid] = 0ull;
    #pragma unroll
    for (int i = 0; i < 7; ++i) {
        int idx = i * 1024 + tid * 4;
        if (idx < CH * Mg) {
            float4 v = *reinterpret_cast<const float4*>(Za + idx);
            *reinterpret_cast<float4*>(zs + idx) = v;
        }
    }
    __syncthreads();                                   // prologue barrier (all V)

    const float* baseW = WbT + b;

    for (int t = 0; t < nsteps; ++t) {
        const int tc = t & (CH - 1);

        // ---- A: sigma, local min, wave reduce -> red
        float s0=0,s1=0,s2=0,s3=0,s4=0,s5=0;
        if (own) {
            float zbv = zs[tc * Mg + tid];
            float inv = (alpha == 0.f) ? 1.f : (1.f / alpha);
            s0 = fmaf(u0, inv, b0 + zbv); s1 = fmaf(u1, inv, b1 + zbv);
            s2 = fmaf(u2, inv, b2 + zbv); s3 = fmaf(u3, inv, b3 + zbv);
            s4 = fmaf(u4, inv, b4 + zbv); s5 = fmaf(u5, inv, b5 + zbv);
        }
        if constexpr (V != 3) {
            float lmin = INFINITY;
            if (own)
                lmin = fminf(fminf(fminf(s0,s1),fminf(s2,s3)),fminf(s4,s5));
            for (int o = 32; o; o >>= 1) lmin = fminf(lmin, __shfl_down(lmin, o));
            if ((tid & 63) == 0) red[tid >> 6] = lmin;
        }
        if constexpr (V != 4) __syncthreads();         // bar1

        // ---- B: global min, pi, argmax, sortable key
        unsigned long long myk = 0ull;
        float sb=0.f, pb=0.f; int bj = 0;
        if (own) {
            float best;
            if constexpr (V == 3) {
                bj = 0; sb = s0; pb = p0; best = s0;
            } else {
                float4 r4 = *reinterpret_cast<const float4*>(red);
                float m1 = 1.f - fminf(fminf(r4.x, r4.y), fminf(r4.z, r4.w));
                best = -INFINITY;
                float sa[6] = {s0,s1,s2,s3,s4,s5};
                float pa[6] = {p0,p1,p2,p3,p4,p5};
                #pragma unroll
                for (int j = 0; j < Nc; ++j) {
                    float pv = (1.f - pa[j]) * (sa[j] + m1);
                    if (pv > best) { best = pv; bj = j; sb = sa[j]; pb = pa[j]; }
                }
            }
            unsigned ub = __float_as_uint(best);
            ub ^= (unsigned)(((int)ub) >> 31) | 0x80000000u;
            myk = ((unsigned long long)ub << 32) | (unsigned long long)(0xFFFFFFFFu - (unsigned)tid);
            lamk[tid] = myk;
        }
        if constexpr (V != 4) __syncthreads();         // bar2

        // ---- C: rank scan, select, psi update
        if (own) {
            float y;
            if constexpr (V == 5) y = fminf(fmaxf(sb, -1.f), 1.f);
            else                  y = tanhf(sb);
            float yv = fmaxf(y, 0.f);
            float dc = fmaxf(y - 0.5f * pb, 0.f);
            int r;
            if constexpr (V == 1) {
                r = (int)((myk >> 13) & 255u);          // fake rank, ~20 hits<25
            } else {
                r = 0;
                const ulonglong2* L = reinterpret_cast<const ulonglong2*>(lamk);
                #pragma unroll
                for (int qq = 0; qq < Mg / 2; ++qq) {
                    ulonglong2 kv = L[qq];
                    r += (kv.x > myk) + (kv.y > myk);
                }
            }
            float d = 0.f;
            if (r < Kk) {
                d = dc;
                sel[r] = ((unsigned long long)(unsigned)((b + bj) * TOT) << 32) |
                         (unsigned long long)__float_as_uint(d);
                ypk[tc * Kk + r] = ((unsigned long long)(unsigned)tid << 32) |
                                   (unsigned long long)__float_as_uint(yv);
            }
            p0 = 0.5f*p0 + ((bj==0)?d:0.f); p1 = 0.5f*p1 + ((bj==1)?d:0.f);
            p2 = 0.5f*p2 + ((bj==2)?d:0.f); p3 = 0.5f*p3 + ((bj==3)?d:0.f);
            p4 = 0.5f*p4 + ((bj==4)?d:0.f); p5 = 0.5f*p5 + ((bj==5)?d:0.f);
        }
        if constexpr (V != 4) __syncthreads();         // bar3

        // ---- E: sel decode, 25-column gather, u/alpha update
        if constexpr (V == 2) {
            u0*=0.5f; u1*=0.5f; u2*=0.5f; u3*=0.5f; u4*=0.5f; u5*=0.5f;
            alpha = fmaf(alpha, 0.5f, 1.0f);
        } else if (own) {
            ulonglong2 sraw[13];
            const ulonglong2* S = reinterpret_cast<const ulonglong2*>(sel);
            #pragma unroll
            for (int qq = 0; qq < 13; ++qq) sraw[qq] = S[qq];
            float sd[Kk]; int so[Kk];
            #pragma unroll
            for (int k = 0; k < Kk; ++k) {
                unsigned long long v = (k & 1) ? sraw[k >> 1].y : sraw[k >> 1].x;
                sd[k] = __uint_as_float((unsigned)v);
                int o = (int)(v >> 32);
                if constexpr (V == 4) o &= 0x1FFFFF;    // clamp racy offsets
                so[k] = o;
            }
            float asum = 0.f;
            #pragma unroll
            for (int k = 0; k < Kk; ++k) asum += sd[k];
            alpha = fmaf(alpha, 0.5f, asum);

            float2 c0[Kk], c1[Kk], c2[Kk];
            #pragma unroll
            for (int k = 0; k < Kk; ++k) {
                const float* cp = baseW + so[k];
                c0[k] = *reinterpret_cast<const float2*>(cp);
                c1[k] = *reinterpret_cast<const float2*>(cp + 2);
                c2[k] = *reinterpret_cast<const float2*>(cp + 4);
            }
            __builtin_amdgcn_sched_barrier(0);
            float a0=0.5f*u0, a1=0.5f*u1, a2=0.5f*u2, a3=0.5f*u3, a4=0.5f*u4, a5=0.5f*u5;
            #pragma unroll
            for (int k = 0; k < Kk; ++k) {
                float dk = sd[k];
                a0 = fmaf(dk, c0[k].x, a0); a1 = fmaf(dk, c0[k].y, a1);
                a2 = fmaf(dk, c1[k].x, a2); a3 = fmaf(dk, c1[k].y, a3);
                a4 = fmaf(dk, c2[k].x, a4); a5 = fmaf(dk, c2[k].y, a5);
            }
            u0=a0; u1=a1; u2=a2; u3=a3; u4=a4; u5=a5;
        }

        // ---- chunk boundary: flush Y ring, stage next Za chunk
        if (tc == CH - 1) {
            const size_t t0 = (size_t)(t - (CH - 1)) * Kk;
            for (int i = tid; i < CH * Kk; i += 256)
                YP[t0 + i] = ypk[i];
            if (t + 1 < nsteps) {
                const float* src = Za + (size_t)(t + 1) * Mg;
                #pragma unroll
                for (int i = 0; i < 7; ++i) {
                    int idx = i * 1024 + tid * 4;
                    if (idx < CH * Mg) {
                        float4 v = *reinterpret_cast<const float4*>(src + idx);
                        *reinterpret_cast<float4*>(zs + idx) = v;
                    }
                }
            }
            if constexpr (V != 4) __syncthreads();
        }
    }

    // ---- epilogue: x_b, phi, psi
    if (own) {
        float inv = (alpha == 0.f) ? 1.f : (1.f / alpha);
        float pa[6] = {p0,p1,p2,p3,p4,p5};
        #pragma unroll
        for (int j = 0; j < Nc; ++j) {
            outTail[b + j]           = pa[j] * inv;
            outTail[TOT + b + j]     = pa[j];
            outTail[2 * TOT + b + j] = pa[j];
        }
    }
}

// ------------------------------------------------- preds = bd + sum val * WdT[idx]
__global__ void preds_k(const unsigned long long* __restrict__ YP,
                        const float* __restrict__ WdT, const float* __restrict__ bd,
                        float* __restrict__ out) {
    const int t = blockIdx.x;
    __shared__ float sv[Kk];
    __shared__ int   si[Kk];
    if (threadIdx.x < Kk) {
        unsigned long long v = YP[(size_t)t * Kk + threadIdx.x];
        sv[threadIdx.x] = __uint_as_float((unsigned)v);
        si[threadIdx.x] = (int)(v >> 32);
    }
    __syncthreads();
    for (int d = threadIdx.x; d < Din; d += 256) {
        float acc = bd[d];
        #pragma unroll
        for (int k = 0; k < Kk; ++k)
            acc = fmaf(sv[k], WdT[(size_t)si[k] * Din + d], acc);
        out[(size_t)t * Din + d] = acc;
    }
}

extern "C" void kernel_launch(void* const* d_in, const int* in_sizes, int n_in,
                              void* d_out, int out_size, void* d_ws, size_t ws_size,
                              hipStream_t stream) {
    const float* X  = (const float*)d_in[0];
    const float* Wa = (const float*)d_in[1];
    const float* ba = (const float*)d_in[2];
    const float* Wb = (const float*)d_in[3];
    const float* bb = (const float*)d_in[4];
    const float* Wd = (const float*)d_in[5];
    const float* bd = (const float*)d_in[6];
    float* out = (float*)d_out;

    float* w    = (float*)d_ws;
    float* Za   = w;                                    // 16384*200
    float* WbT  = Za  + (size_t)Tn * Mg;                // 1200*1200
    float* WdT  = WbT + (size_t)TOT * TOT;              // 200*784
    unsigned long long* YP =
        (unsigned long long*)(WdT + (size_t)Mg * Din);  // 16384*25 u64

    dim3 tb(32, 8);
    transpose_k<<<dim3((TOT + 31) / 32, (TOT + 31) / 32), tb, 0, stream>>>(Wb, WbT, TOT, TOT);
    transpose_k<<<dim3((Mg + 31) / 32, (Din + 31) / 32), tb, 0, stream>>>(Wd, WdT, Din, Mg);
    za_k<<<Tn / 16, 256, 0, stream>>>(X, Wa, ba, Za);

    float* outTail = out + (size_t)Tn * Din;
    // ---- ablation probes (scratch-quality results, fully overwritten by V0)
    serial_t<1><<<1, 256, 0, stream>>>(Za, WbT, bb, YP, outTail, 4096);  // no scan
    serial_t<2><<<1, 256, 0, stream>>>(Za, WbT, bb, YP, outTail, 4096);  // no gather
    serial_t<3><<<1, 256, 0, stream>>>(Za, WbT, bb, YP, outTail, 4096);  // no min/argmax
    serial_t<4><<<1, 256, 0, stream>>>(Za, WbT, bb, YP, outTail, 4096);  // no barriers
    serial_t<5><<<1, 256, 0, stream>>>(Za, WbT, bb, YP, outTail, 4096);  // no tanh
    // ---- the real run (last; overwrites YP + outTail entirely)
    serial_t<0><<<1, 256, 0, stream>>>(Za, WbT, bb, YP, outTail, Tn);
    preds_k<<<Tn, 256, 0, stream>>>(YP, WdT, bd, out);
}

// Round 9
// 75390.515 us; speedup vs baseline: 1.9476x; 1.9476x over previous
//
#include <hip/hip_runtime.h>
#include <math.h>

#define Tn   16384
#define Mg   200
#define Nc   6
#define TOT  1200
#define Kk   25
#define Din  784

// ---------------------------------------------------------------- transpose
__global__ void transpose_k(const float* __restrict__ src, float* __restrict__ dst,
                            int R, int C) {
    __shared__ float tile[32][33];
    int bx = blockIdx.x * 32, by = blockIdx.y * 32;
    int x = bx + threadIdx.x;
    for (int j = 0; j < 32; j += 8) {
        int y = by + threadIdx.y + j;
        if (x < C && y < R) tile[threadIdx.y + j][threadIdx.x] = src[(size_t)y * C + x];
    }
    __syncthreads();
    int x2 = by + threadIdx.x;
    for (int j = 0; j < 32; j += 8) {
        int y2 = bx + threadIdx.y + j;
        if (x2 < R && y2 < C) dst[(size_t)y2 * R + x2] = tile[threadIdx.x][threadIdx.y + j];
    }
}

// ------------------------------------------------- Za = X @ Wa^T + ba  (16384 x 200)
__global__ void za_k(const float* __restrict__ X, const float* __restrict__ Wa,
                     const float* __restrict__ ba, float* __restrict__ Za) {
    __shared__ float xs[16][788];
    const int tid = threadIdx.x;
    const int t0  = blockIdx.x * 16;
    for (int idx = tid; idx < 16 * Din; idx += 256) {
        int tt = idx / Din, kk = idx - tt * Din;
        xs[tt][kk] = X[(size_t)(t0 + tt) * Din + kk];
    }
    __syncthreads();
    const int tq = tid & 15, gq = tid >> 4;
    const float4* xrow = reinterpret_cast<const float4*>(&xs[tq][0]);
    for (int g = gq; g < Mg; g += 16) {
        float acc = ba[g];
        const float4* wrow = reinterpret_cast<const float4*>(Wa + (size_t)g * Din);
        for (int k4 = 0; k4 < Din / 4; ++k4) {
            float4 a = xrow[k4], b = wrow[k4];
            acc = fmaf(a.x, b.x, acc); acc = fmaf(a.y, b.y, acc);
            acc = fmaf(a.z, b.z, acc); acc = fmaf(a.w, b.w, acc);
        }
        Za[(size_t)(t0 + tq) * Mg + g] = acc;
    }
}

// ------------------------------------------------------------- serial recurrence
// Wave-specialized, 2 barriers/step. Wave0 (64 lanes): ALL serial decisions with
// zero sync -- sigma, global min (shfl), per-group argmax, ballot quickselect
// top-25 (R6-proven), psi/alpha updates, sel publish. Waves 1-5 (300 active
// threads): the 25-column x 1200-element gather u' = 0.5u + sum d_k*col_k,
// each thread owning one float4 of u (in LDS).
__launch_bounds__(384, 1)
__global__ void serial_k(const float* __restrict__ Za, const float* __restrict__ WbT,
                         const float* __restrict__ bb,
                         unsigned long long* __restrict__ YP,
                         float* __restrict__ outTail) {
    __shared__ alignas(16) float u_sh[TOT];                // 4.8 KB
    __shared__ alignas(16) unsigned long long sel[26];

    const int tid = threadIdx.x;

    if (tid < TOT / 4)
        *reinterpret_cast<float4*>(u_sh + 4 * tid) = make_float4(0.f, 0.f, 0.f, 0.f);
    if (tid == 383) sel[25] = 0ull;
    __syncthreads();

    if (tid < 64) {
        // ================= wave0: serial decision core =================
        const int lane = tid;
        const bool grp = (lane < 50);
        const int cell0 = 24 * lane;
        const unsigned long long lt = (1ull << lane) - 1ull;

        float u[24], ps[24], cb[24];
        #pragma unroll
        for (int i = 0; i < 24; ++i) { u[i] = 0.f; ps[i] = 0.f; cb[i] = 0.f; }
        if (grp) {
            #pragma unroll
            for (int q = 0; q < 6; ++q) {
                float4 v = *reinterpret_cast<const float4*>(bb + cell0 + 4 * q);
                cb[4*q] = v.x; cb[4*q+1] = v.y; cb[4*q+2] = v.z; cb[4*q+3] = v.w;
            }
        }
        float alpha = 0.f;
        float4 za4 = make_float4(0.f, 0.f, 0.f, 0.f);
        if (grp) za4 = *reinterpret_cast<const float4*>(Za + 4 * lane);

        for (int t = 0; t < Tn; ++t) {
            // prefetch next za (hidden under quickselect)
            float4 zan = make_float4(0.f, 0.f, 0.f, 0.f);
            if (grp && t + 1 < Tn)
                zan = *reinterpret_cast<const float4*>(Za + (size_t)(t + 1) * Mg + 4 * lane);

            // read current u (written by gather waves last step)
            if (grp) {
                #pragma unroll
                for (int q = 0; q < 6; ++q) {
                    float4 v = *reinterpret_cast<const float4*>(u_sh + cell0 + 4 * q);
                    u[4*q] = v.x; u[4*q+1] = v.y; u[4*q+2] = v.z; u[4*q+3] = v.w;
                }
            }
            const float inv = (alpha == 0.f) ? 1.f : (1.f / alpha);

            // pass 1: sigma in place, local min
            float lm = INFINITY;
            if (grp) {
                #pragma unroll
                for (int c = 0; c < 4; ++c) {
                    float zc = (c==0)?za4.x:(c==1)?za4.y:(c==2)?za4.z:za4.w;
                    #pragma unroll
                    for (int j = 0; j < 6; ++j) {
                        int i = 6 * c + j;
                        u[i] = fmaf(u[i], inv, cb[i] + zc);   // u[] now holds sigma
                        lm = fminf(lm, u[i]);
                    }
                }
            }
            #pragma unroll
            for (int o = 1; o < 64; o <<= 1) lm = fminf(lm, __shfl_xor(lm, o));
            const float m1 = 1.f - lm;

            // pass 2: per-group argmax of pi, sortable keys
            float bs[4], bp[4]; int bj[4]; unsigned long long kb[4];
            #pragma unroll
            for (int c = 0; c < 4; ++c) { bs[c]=0.f; bp[c]=0.f; bj[c]=0; kb[c]=0ull; }
            if (grp) {
                #pragma unroll
                for (int c = 0; c < 4; ++c) {
                    float best = -INFINITY, sbv = 0.f, pbv = 0.f; int jb = 0;
                    #pragma unroll
                    for (int j = 0; j < 6; ++j) {
                        int i = 6 * c + j;
                        float pv = (1.f - ps[i]) * (u[i] + m1);
                        bool bet = pv > best;
                        best = bet ? pv : best;
                        jb  = bet ? j : jb;
                        sbv = bet ? u[i] : sbv;
                        pbv = bet ? ps[i] : pbv;
                    }
                    unsigned ub = __float_as_uint(best);
                    ub ^= (unsigned)(((int)ub) >> 31) | 0x80000000u;
                    int g = 4 * lane + c;
                    kb[c] = ((unsigned long long)ub << 32) |
                            (unsigned long long)(0xFFFFFFFFu - (unsigned)g);
                    bs[c] = sbv; bp[c] = pbv; bj[c] = jb;
                }
            }

            // ballot quickselect: theta = 25th-largest key (exact, R6-proven)
            unsigned long long A = 0ull, B = ~0ull;
            unsigned long long p = __shfl(kb[0], 0);
            unsigned long long theta;
            while (true) {
                int cnt = __popcll(__ballot(kb[0] >= p)) + __popcll(__ballot(kb[1] >= p))
                        + __popcll(__ballot(kb[2] >= p)) + __popcll(__ballot(kb[3] >= p));
                if (cnt == Kk) { theta = p; break; }
                if (cnt > Kk) A = p; else B = p;
                unsigned long long m0 = __ballot(kb[0] > A && kb[0] < B);
                unsigned long long m1b = __ballot(kb[1] > A && kb[1] < B);
                unsigned long long m2 = __ballot(kb[2] > A && kb[2] < B);
                unsigned long long m3 = __ballot(kb[3] > A && kb[3] < B);
                int cls; unsigned long long mm;
                if (m0)       { cls = 0; mm = m0; }
                else if (m1b) { cls = 1; mm = m1b; }
                else if (m2)  { cls = 2; mm = m2; }
                else          { cls = 3; mm = m3; }
                int sl = __ffsll(mm) - 1;
                unsigned long long kc = (cls==0)?kb[0]:(cls==1)?kb[1]:(cls==2)?kb[2]:kb[3];
                p = __shfl(kc, sl);
            }

            // selection: deterministic slots (class-major, then lane)
            unsigned long long M0 = __ballot(kb[0] >= theta);
            unsigned long long M1 = __ballot(kb[1] >= theta);
            unsigned long long M2 = __ballot(kb[2] >= theta);
            unsigned long long M3 = __ballot(kb[3] >= theta);
            int base1 = __popcll(M0);
            int base2 = base1 + __popcll(M1);
            int base3 = base2 + __popcll(M2);

            float dsum = 0.f;
            #pragma unroll
            for (int c = 0; c < 4; ++c) {
                unsigned long long Mc = (c==0)?M0:(c==1)?M1:(c==2)?M2:M3;
                int bse = (c==0)?0:(c==1)?base1:(c==2)?base2:base3;
                bool s = grp && (kb[c] >= theta);
                float d = 0.f;
                if (s) {
                    int slot = bse + __popcll(Mc & lt);
                    float x = fminf(fmaxf(bs[c], -9.f), 9.f);
                    float e = __expf(2.f * x);
                    float y = 1.f - 2.f / (e + 1.f);
                    float yv = fmaxf(y, 0.f);
                    d = fmaxf(y - 0.5f * bp[c], 0.f);
                    int g = 4 * lane + c;
                    int eix = 6 * g + bj[c];
                    sel[slot] = ((unsigned long long)(unsigned)(eix * TOT) << 32) |
                                (unsigned long long)__float_as_uint(d);
                    YP[(size_t)t * Kk + slot] =
                        ((unsigned long long)(unsigned)g << 32) |
                        (unsigned long long)__float_as_uint(yv);
                }
                dsum += d;
                #pragma unroll
                for (int j = 0; j < 6; ++j) {
                    int i = 6 * c + j;
                    float add = (j == bj[c]) ? d : 0.f;
                    ps[i] = fmaf(ps[i], 0.5f, add);
                }
            }
            // alpha = 0.5*alpha + sum(d) via wave reduce
            #pragma unroll
            for (int o = 1; o < 64; o <<= 1) dsum += __shfl_xor(dsum, o);
            alpha = fmaf(alpha, 0.5f, dsum);

            __syncthreads();                   // bar A: sel published
            __syncthreads();                   // bar B: u_sh updated by gather
            za4 = zan;
        }

        // epilogue: x_b, phi, psi
        if (grp) {
            float inv2 = (alpha == 0.f) ? 1.f : (1.f / alpha);
            #pragma unroll
            for (int i = 0; i < 24; ++i) {
                outTail[cell0 + i]           = ps[i] * inv2;
                outTail[TOT + cell0 + i]     = ps[i];
                outTail[2 * TOT + cell0 + i] = ps[i];
            }
        }
    } else {
        // ================= waves 1-5: parallel column gather =================
        const int j = tid - 64;                // 0..319; active j<300 own f4 block j
        const bool act = (j < 300);
        float* up = u_sh + 4 * j;

        for (int t = 0; t < Tn; ++t) {
            float4 uo = make_float4(0.f, 0.f, 0.f, 0.f);
            if (act) {
                uo = *reinterpret_cast<const float4*>(up);
                uo.x *= 0.5f; uo.y *= 0.5f; uo.z *= 0.5f; uo.w *= 0.5f;
            }
            __syncthreads();                   // bar A: sel ready

            ulonglong2 sr[13];
            const ulonglong2* S = reinterpret_cast<const ulonglong2*>(sel);
            #pragma unroll
            for (int q = 0; q < 13; ++q) sr[q] = S[q];
            float sd[Kk]; int so[Kk];
            #pragma unroll
            for (int k = 0; k < Kk; ++k) {
                unsigned long long v = (k & 1) ? sr[k >> 1].y : sr[k >> 1].x;
                sd[k] = __uint_as_float((unsigned)v);
                so[k] = (int)(v >> 32);
            }
            if (act) {
                float4 c[Kk];
                #pragma unroll
                for (int k = 0; k < Kk; ++k)
                    c[k] = *reinterpret_cast<const float4*>(WbT + so[k] + 4 * j);
                __builtin_amdgcn_sched_barrier(0);   // keep loads clustered
                #pragma unroll
                for (int k = 0; k < Kk; ++k) {
                    float dk = sd[k];
                    uo.x = fmaf(dk, c[k].x, uo.x);
                    uo.y = fmaf(dk, c[k].y, uo.y);
                    uo.z = fmaf(dk, c[k].z, uo.z);
                    uo.w = fmaf(dk, c[k].w, uo.w);
                }
                *reinterpret_cast<float4*>(up) = uo;
            }
            __syncthreads();                   // bar B: u_sh updated
        }
    }
}

// ------------------------------------------------- preds = bd + sum val * WdT[idx]
__global__ void preds_k(const unsigned long long* __restrict__ YP,
                        const float* __restrict__ WdT, const float* __restrict__ bd,
                        float* __restrict__ out) {
    const int t = blockIdx.x;
    __shared__ float sv[Kk];
    __shared__ int   si[Kk];
    if (threadIdx.x < Kk) {
        unsigned long long v = YP[(size_t)t * Kk + threadIdx.x];
        sv[threadIdx.x] = __uint_as_float((unsigned)v);
        si[threadIdx.x] = (int)(v >> 32);
    }
    __syncthreads();
    for (int d = threadIdx.x; d < Din; d += 256) {
        float acc = bd[d];
        #pragma unroll
        for (int k = 0; k < Kk; ++k)
            acc = fmaf(sv[k], WdT[(size_t)si[k] * Din + d], acc);
        out[(size_t)t * Din + d] = acc;
    }
}

extern "C" void kernel_launch(void* const* d_in, const int* in_sizes, int n_in,
                              void* d_out, int out_size, void* d_ws, size_t ws_size,
                              hipStream_t stream) {
    const float* X  = (const float*)d_in[0];
    const float* Wa = (const float*)d_in[1];
    const float* ba = (const float*)d_in[2];
    const float* Wb = (const float*)d_in[3];
    const float* bb = (const float*)d_in[4];
    const float* Wd = (const float*)d_in[5];
    const float* bd = (const float*)d_in[6];
    float* out = (float*)d_out;

    float* w    = (float*)d_ws;
    float* Za   = w;                                    // 16384*200
    float* WbT  = Za  + (size_t)Tn * Mg;                // 1200*1200
    float* WdT  = WbT + (size_t)TOT * TOT;              // 200*784
    unsigned long long* YP =
        (unsigned long long*)(WdT + (size_t)Mg * Din);  // 16384*25 u64

    dim3 tb(32, 8);
    transpose_k<<<dim3((TOT + 31) / 32, (TOT + 31) / 32), tb, 0, stream>>>(Wb, WbT, TOT, TOT);
    transpose_k<<<dim3((Mg + 31) / 32, (Din + 31) / 32), tb, 0, stream>>>(Wd, WdT, Din, Mg);
    za_k<<<Tn / 16, 256, 0, stream>>>(X, Wa, ba, Za);
    serial_k<<<1, 384, 0, stream>>>(Za, WbT, bb, YP, out + (size_t)Tn * Din);
    preds_k<<<Tn, 256, 0, stream>>>(YP, WdT, bd, out);
}

// Round 10
// 72824.847 us; speedup vs baseline: 2.0162x; 1.0352x over previous
//
#include <hip/hip_runtime.h>
#include <math.h>

#define Tn   16384
#define Mg   200
#define Nc   6
#define TOT  1200
#define Kk   25
#define Din  784
#define SP   28     // padded words per 24-cell block of sigma_sh

// ---------------------------------------------------------------- transpose
__global__ void transpose_k(const float* __restrict__ src, float* __restrict__ dst,
                            int R, int C) {
    __shared__ float tile[32][33];
    int bx = blockIdx.x * 32, by = blockIdx.y * 32;
    int x = bx + threadIdx.x;
    for (int j = 0; j < 32; j += 8) {
        int y = by + threadIdx.y + j;
        if (x < C && y < R) tile[threadIdx.y + j][threadIdx.x] = src[(size_t)y * C + x];
    }
    __syncthreads();
    int x2 = by + threadIdx.x;
    for (int j = 0; j < 32; j += 8) {
        int y2 = bx + threadIdx.y + j;
        if (x2 < R && y2 < C) dst[(size_t)y2 * R + x2] = tile[threadIdx.x][threadIdx.y + j];
    }
}

// ------------------------------------------------- Za = X @ Wa^T + ba  (16384 x 200)
__global__ void za_k(const float* __restrict__ X, const float* __restrict__ Wa,
                     const float* __restrict__ ba, float* __restrict__ Za) {
    __shared__ float xs[16][788];
    const int tid = threadIdx.x;
    const int t0  = blockIdx.x * 16;
    for (int idx = tid; idx < 16 * Din; idx += 256) {
        int tt = idx / Din, kk = idx - tt * Din;
        xs[tt][kk] = X[(size_t)(t0 + tt) * Din + kk];
    }
    __syncthreads();
    const int tq = tid & 15, gq = tid >> 4;
    const float4* xrow = reinterpret_cast<const float4*>(&xs[tq][0]);
    for (int g = gq; g < Mg; g += 16) {
        float acc = ba[g];
        const float4* wrow = reinterpret_cast<const float4*>(Wa + (size_t)g * Din);
        for (int k4 = 0; k4 < Din / 4; ++k4) {
            float4 a = xrow[k4], b = wrow[k4];
            acc = fmaf(a.x, b.x, acc); acc = fmaf(a.y, b.y, acc);
            acc = fmaf(a.z, b.z, acc); acc = fmaf(a.w, b.w, acc);
        }
        Za[(size_t)(t0 + tq) * Mg + g] = acc;
    }
}

// ------------------------------------------------------------- serial recurrence
// Wave0: decision only (argmax keys, ballot quickselect top-25, psi/alpha, sel
// publish). Waves 1-5: u state IN REGISTERS (1 float4/thread), 25-col gather,
// then sigma_{t+1} + min partials (so wave0 never touches u). sel broadcast via
// lane-split LDS read + v_readlane (2 LDS instr/wave). 2 barriers/step.
__launch_bounds__(384, 1)
__global__ void serial_k(const float* __restrict__ Za, const float* __restrict__ WbT,
                         const float* __restrict__ bb,
                         unsigned long long* __restrict__ YP,
                         float* __restrict__ outTail) {
    __shared__ alignas(16) float sigma_sh[50 * SP];   // padded, 5.6 KB
    __shared__ alignas(16) float minp[8];
    __shared__ alignas(16) float selD[32];
    __shared__ alignas(16) int   selO[32];
    __shared__ float alphaS;

    const int tid  = threadIdx.x;
    const int lane = tid & 63;

    if (tid < 64) {
        // ================= wave0: decision core =================
        const bool grp = (lane < 50);
        const int sgb  = lane * SP;
        const int cell0 = 24 * lane;
        const unsigned long long lt = (1ull << lane) - 1ull;

        float ps[24];
        #pragma unroll
        for (int i = 0; i < 24; ++i) ps[i] = 0.f;
        float alpha = 0.f;

        __syncthreads();                       // prologue: sigma_0 ready

        for (int t = 0; t < Tn; ++t) {
            // global min from 5 wave partials
            float4 mp4 = *reinterpret_cast<const float4*>(minp);
            float m = fminf(fminf(fminf(mp4.x, mp4.y), fminf(mp4.z, mp4.w)), minp[4]);
            const float m1 = 1.f - m;

            // my 24 sigma values
            float sg[24];
            if (grp) {
                #pragma unroll
                for (int q = 0; q < 6; ++q) {
                    float4 v = *reinterpret_cast<const float4*>(sigma_sh + sgb + 4 * q);
                    sg[4*q] = v.x; sg[4*q+1] = v.y; sg[4*q+2] = v.z; sg[4*q+3] = v.w;
                }
            } else {
                #pragma unroll
                for (int i = 0; i < 24; ++i) sg[i] = 0.f;
            }

            // per-group argmax of pi, sortable keys
            float bs[4], bp[4]; int bj[4]; unsigned long long kb[4];
            #pragma unroll
            for (int c = 0; c < 4; ++c) { bs[c]=0.f; bp[c]=0.f; bj[c]=0; kb[c]=0ull; }
            if (grp) {
                #pragma unroll
                for (int c = 0; c < 4; ++c) {
                    float best = -INFINITY, sbv = 0.f, pbv = 0.f; int jb = 0;
                    #pragma unroll
                    for (int j = 0; j < 6; ++j) {
                        int i = 6 * c + j;
                        float pv = (1.f - ps[i]) * (sg[i] + m1);
                        bool bet = pv > best;
                        best = bet ? pv : best;
                        jb  = bet ? j : jb;
                        sbv = bet ? sg[i] : sbv;
                        pbv = bet ? ps[i] : pbv;
                    }
                    unsigned ub = __float_as_uint(best);
                    ub ^= (unsigned)(((int)ub) >> 31) | 0x80000000u;
                    int g = 4 * lane + c;
                    kb[c] = ((unsigned long long)ub << 32) |
                            (unsigned long long)(0xFFFFFFFFu - (unsigned)g);
                    bs[c] = sbv; bp[c] = pbv; bj[c] = jb;
                }
            }

            // ballot quickselect: theta = 25th-largest key (exact)
            unsigned long long A = 0ull, B = ~0ull;
            unsigned long long p = __shfl(kb[0], 0);
            unsigned long long theta;
            while (true) {
                int cnt = __popcll(__ballot(kb[0] >= p)) + __popcll(__ballot(kb[1] >= p))
                        + __popcll(__ballot(kb[2] >= p)) + __popcll(__ballot(kb[3] >= p));
                if (cnt == Kk) { theta = p; break; }
                if (cnt > Kk) A = p; else B = p;
                unsigned long long m0 = __ballot(kb[0] > A && kb[0] < B);
                unsigned long long m1b = __ballot(kb[1] > A && kb[1] < B);
                unsigned long long m2 = __ballot(kb[2] > A && kb[2] < B);
                unsigned long long m3 = __ballot(kb[3] > A && kb[3] < B);
                int cls; unsigned long long mm;
                if (m0)       { cls = 0; mm = m0; }
                else if (m1b) { cls = 1; mm = m1b; }
                else if (m2)  { cls = 2; mm = m2; }
                else          { cls = 3; mm = m3; }
                int sl = __ffsll(mm) - 1;
                unsigned long long kc = (cls==0)?kb[0]:(cls==1)?kb[1]:(cls==2)?kb[2]:kb[3];
                p = __shfl(kc, sl);
            }

            unsigned long long M0 = __ballot(kb[0] >= theta);
            unsigned long long M1 = __ballot(kb[1] >= theta);
            unsigned long long M2 = __ballot(kb[2] >= theta);
            unsigned long long M3 = __ballot(kb[3] >= theta);
            int base1 = __popcll(M0);
            int base2 = base1 + __popcll(M1);
            int base3 = base2 + __popcll(M2);

            float dsum = 0.f;
            int slotr[4]; unsigned long long yv64[4];
            #pragma unroll
            for (int c = 0; c < 4; ++c) {
                slotr[c] = -1; yv64[c] = 0ull;
                unsigned long long Mc = (c==0)?M0:(c==1)?M1:(c==2)?M2:M3;
                int bse = (c==0)?0:(c==1)?base1:(c==2)?base2:base3;
                bool s = grp && (kb[c] >= theta);
                float d = 0.f;
                if (s) {
                    int slot = bse + __popcll(Mc & lt);
                    float x = fminf(fmaxf(bs[c], -9.f), 9.f);
                    float e = __expf(2.f * x);
                    float y = 1.f - 2.f / (e + 1.f);
                    float yv = fmaxf(y, 0.f);
                    d = fmaxf(y - 0.5f * bp[c], 0.f);
                    int g = 4 * lane + c;
                    selD[slot] = d;
                    selO[slot] = (6 * g + bj[c]) * TOT;
                    slotr[c] = slot;
                    yv64[c] = ((unsigned long long)(unsigned)g << 32) |
                              (unsigned long long)__float_as_uint(yv);
                }
                dsum += d;
                #pragma unroll
                for (int j = 0; j < 6; ++j) {
                    int i = 6 * c + j;
                    float add = (j == bj[c]) ? d : 0.f;
                    ps[i] = fmaf(ps[i], 0.5f, add);
                }
            }
            #pragma unroll
            for (int o = 1; o < 64; o <<= 1) dsum += __shfl_xor(dsum, o);
            alpha = fmaf(alpha, 0.5f, dsum);
            if (lane == 0) alphaS = (alpha == 0.f) ? 1.f : alpha;

            __syncthreads();                   // bar A: sel published
            // shadow region: YP stores hidden under gather
            #pragma unroll
            for (int c = 0; c < 4; ++c)
                if (slotr[c] >= 0) YP[(size_t)t * Kk + slotr[c]] = yv64[c];
            __syncthreads();                   // bar B: sigma_{t+1} ready
        }

        if (grp) {
            float inv2 = (alpha == 0.f) ? 1.f : (1.f / alpha);
            #pragma unroll
            for (int i = 0; i < 24; ++i) {
                outTail[cell0 + i]           = ps[i] * inv2;
                outTail[TOT + cell0 + i]     = ps[i];
                outTail[2 * TOT + cell0 + i] = ps[i];
            }
        }
    } else {
        // ================= waves 1-5: gather + sigma =================
        const int j = tid - 64;                 // 0..319, active j<300
        const bool act = (j < 300);
        const int w = (tid >> 6) - 1;           // 0..4
        const int base = act ? 4 * j : 0;
        const int saddr = act ? ((j / 6) * SP + (4 * j) % 24) : 0;
        const int g0 = base / 6, g1 = (base + 3) / 6;
        const bool f1 = ((base + 1) / 6) != g0;
        const bool f2 = ((base + 2) / 6) != g0;
        const bool f3 = ((base + 3) / 6) != g0;

        float4 cb4 = make_float4(0.f, 0.f, 0.f, 0.f);
        if (act) cb4 = *reinterpret_cast<const float4*>(bb + base);
        float za0 = act ? Za[g0] : 0.f;
        float za1 = act ? Za[g1] : 0.f;
        float4 uo = make_float4(0.f, 0.f, 0.f, 0.f);

        // sigma_0 = cb + za (u=0)
        {
            float s0 = cb4.x + za0;
            float s1 = cb4.y + (f1 ? za1 : za0);
            float s2 = cb4.z + (f2 ? za1 : za0);
            float s3 = cb4.w + (f3 ? za1 : za0);
            if (act)
                *reinterpret_cast<float4*>(sigma_sh + saddr) = make_float4(s0,s1,s2,s3);
            float lm = act ? fminf(fminf(s0, s1), fminf(s2, s3)) : INFINITY;
            #pragma unroll
            for (int o = 1; o < 64; o <<= 1) lm = fminf(lm, __shfl_xor(lm, o));
            if (lane == 0) minp[w] = lm;
        }
        __syncthreads();                        // prologue barrier

        for (int t = 0; t < Tn; ++t) {
            // prefetch za_{t+1} (hidden under wave0 decision)
            const int tn = (t + 1 < Tn) ? t + 1 : t;
            float nza0 = act ? Za[(size_t)tn * Mg + g0] : 0.f;
            float nza1 = act ? Za[(size_t)tn * Mg + g1] : 0.f;
            uo.x *= 0.5f; uo.y *= 0.5f; uo.z *= 0.5f; uo.w *= 0.5f;

            __syncthreads();                    // bar A: sel ready

            float vD = 0.f; int vO = 0;
            if (lane < 25) { vD = selD[lane]; vO = selO[lane]; }
            const float av  = alphaS;
            const float inv = 1.f / av;

            float4 cc[Kk];
            #pragma unroll
            for (int k = 0; k < Kk; ++k) {
                int offk = __builtin_amdgcn_readlane(vO, k);     // SGPR, uniform
                cc[k] = *reinterpret_cast<const float4*>(WbT + offk + base);
            }
            __builtin_amdgcn_sched_barrier(0);  // keep loads clustered
            #pragma unroll
            for (int k = 0; k < Kk; ++k) {
                float dk = __uint_as_float(
                    (unsigned)__builtin_amdgcn_readlane((int)__float_as_uint(vD), k));
                uo.x = fmaf(dk, cc[k].x, uo.x);
                uo.y = fmaf(dk, cc[k].y, uo.y);
                uo.z = fmaf(dk, cc[k].z, uo.z);
                uo.w = fmaf(dk, cc[k].w, uo.w);
            }

            // sigma_{t+1} = u*inv + cb + za_{t+1}; min partial
            float s0 = fmaf(uo.x, inv, cb4.x + nza0);
            float s1 = fmaf(uo.y, inv, cb4.y + (f1 ? nza1 : nza0));
            float s2 = fmaf(uo.z, inv, cb4.z + (f2 ? nza1 : nza0));
            float s3 = fmaf(uo.w, inv, cb4.w + (f3 ? nza1 : nza0));
            if (act)
                *reinterpret_cast<float4*>(sigma_sh + saddr) = make_float4(s0,s1,s2,s3);
            float lm = act ? fminf(fminf(s0, s1), fminf(s2, s3)) : INFINITY;
            #pragma unroll
            for (int o = 1; o < 64; o <<= 1) lm = fminf(lm, __shfl_xor(lm, o));
            if (lane == 0) minp[w] = lm;

            __syncthreads();                    // bar B: sigma published
        }
    }
}

// ------------------------------------------------- preds = bd + sum val * WdT[idx]
__global__ void preds_k(const unsigned long long* __restrict__ YP,
                        const float* __restrict__ WdT, const float* __restrict__ bd,
                        float* __restrict__ out) {
    const int t = blockIdx.x;
    __shared__ float sv[Kk];
    __shared__ int   si[Kk];
    if (threadIdx.x < Kk) {
        unsigned long long v = YP[(size_t)t * Kk + threadIdx.x];
        sv[threadIdx.x] = __uint_as_float((unsigned)v);
        si[threadIdx.x] = (int)(v >> 32);
    }
    __syncthreads();
    for (int d = threadIdx.x; d < Din; d += 256) {
        float acc = bd[d];
        #pragma unroll
        for (int k = 0; k < Kk; ++k)
            acc = fmaf(sv[k], WdT[(size_t)si[k] * Din + d], acc);
        out[(size_t)t * Din + d] = acc;
    }
}

extern "C" void kernel_launch(void* const* d_in, const int* in_sizes, int n_in,
                              void* d_out, int out_size, void* d_ws, size_t ws_size,
                              hipStream_t stream) {
    const float* X  = (const float*)d_in[0];
    const float* Wa = (const float*)d_in[1];
    const float* ba = (const float*)d_in[2];
    const float* Wb = (const float*)d_in[3];
    const float* bb = (const float*)d_in[4];
    const float* Wd = (const float*)d_in[5];
    const float* bd = (const float*)d_in[6];
    float* out = (float*)d_out;

    float* w    = (float*)d_ws;
    float* Za   = w;                                    // 16384*200
    float* WbT  = Za  + (size_t)Tn * Mg;                // 1200*1200
    float* WdT  = WbT + (size_t)TOT * TOT;              // 200*784
    unsigned long long* YP =
        (unsigned long long*)(WdT + (size_t)Mg * Din);  // 16384*25 u64

    dim3 tb(32, 8);
    transpose_k<<<dim3((TOT + 31) / 32, (TOT + 31) / 32), tb, 0, stream>>>(Wb, WbT, TOT, TOT);
    transpose_k<<<dim3((Mg + 31) / 32, (Din + 31) / 32), tb, 0, stream>>>(Wd, WdT, Din, Mg);
    za_k<<<Tn / 16, 256, 0, stream>>>(X, Wa, ba, Za);
    serial_k<<<1, 384, 0, stream>>>(Za, WbT, bb, YP, out + (size_t)Tn * Din);
    preds_k<<<Tn, 256, 0, stream>>>(YP, WdT, bd, out);
}

// Round 11
// 71346.002 us; speedup vs baseline: 2.0580x; 1.0207x over previous
//
#include <hip/hip_runtime.h>
#include <math.h>

#define Tn   16384
#define Mg   200
#define Nc   6
#define TOT  1200
#define Kk   25
#define Din  784
#define SP   28     // padded words per 24-cell block of sigma_sh

// ---------------------------------------------------------------- transpose
__global__ void transpose_k(const float* __restrict__ src, float* __restrict__ dst,
                            int R, int C) {
    __shared__ float tile[32][33];
    int bx = blockIdx.x * 32, by = blockIdx.y * 32;
    int x = bx + threadIdx.x;
    for (int j = 0; j < 32; j += 8) {
        int y = by + threadIdx.y + j;
        if (x < C && y < R) tile[threadIdx.y + j][threadIdx.x] = src[(size_t)y * C + x];
    }
    __syncthreads();
    int x2 = by + threadIdx.x;
    for (int j = 0; j < 32; j += 8) {
        int y2 = bx + threadIdx.y + j;
        if (x2 < R && y2 < C) dst[(size_t)y2 * R + x2] = tile[threadIdx.x][threadIdx.y + j];
    }
}

// ------------------------------------------------- Za = X @ Wa^T + ba  (16384 x 200)
__global__ void za_k(const float* __restrict__ X, const float* __restrict__ Wa,
                     const float* __restrict__ ba, float* __restrict__ Za) {
    __shared__ float xs[16][788];
    const int tid = threadIdx.x;
    const int t0  = blockIdx.x * 16;
    for (int idx = tid; idx < 16 * Din; idx += 256) {
        int tt = idx / Din, kk = idx - tt * Din;
        xs[tt][kk] = X[(size_t)(t0 + tt) * Din + kk];
    }
    __syncthreads();
    const int tq = tid & 15, gq = tid >> 4;
    const float4* xrow = reinterpret_cast<const float4*>(&xs[tq][0]);
    for (int g = gq; g < Mg; g += 16) {
        float acc = ba[g];
        const float4* wrow = reinterpret_cast<const float4*>(Wa + (size_t)g * Din);
        for (int k4 = 0; k4 < Din / 4; ++k4) {
            float4 a = xrow[k4], b = wrow[k4];
            acc = fmaf(a.x, b.x, acc); acc = fmaf(a.y, b.y, acc);
            acc = fmaf(a.z, b.z, acc); acc = fmaf(a.w, b.w, acc);
        }
        Za[(size_t)(t0 + tq) * Mg + g] = acc;
    }
}

// ------------------------------------------------------------- serial recurrence
// Wave0: decision (argmax keys, warm-started ballot quickselect, sel publish).
// psi update + YP stores shadowed after barA/barB. Waves 1-5: u in registers,
// 25-col gather, redundant per-wave alpha recurrence (hidden under load wait),
// sigma_{t+1} + min partials. 2 barriers/step; no VMEM op drains on the
// critical path.
__launch_bounds__(384, 1)
__global__ void serial_k(const float* __restrict__ Za, const float* __restrict__ WbT,
                         const float* __restrict__ bb,
                         unsigned long long* __restrict__ YP,
                         float* __restrict__ outTail) {
    __shared__ alignas(16) float sigma_sh[50 * SP];   // padded, 5.6 KB
    __shared__ alignas(16) float minp[8];
    __shared__ alignas(16) float selD[32];
    __shared__ alignas(16) int   selO[32];
    __shared__ float alphaS;

    const int tid  = threadIdx.x;
    const int lane = tid & 63;

    if (tid < 64) {
        // ================= wave0: decision core =================
        const bool grp = (lane < 50);
        const int sgb  = lane * SP;
        const int cell0 = 24 * lane;
        const unsigned long long lt = (1ull << lane) - 1ull;

        float ps[24];
        #pragma unroll
        for (int i = 0; i < 24; ++i) ps[i] = 0.f;
        unsigned long long thw = 0ull;          // warm pivot across steps
        int slotr[4] = {-1, -1, -1, -1};
        unsigned long long yv64[4] = {0ull, 0ull, 0ull, 0ull};
        int bj[4] = {0, 0, 0, 0};
        float dcl[4] = {0.f, 0.f, 0.f, 0.f};

        __syncthreads();                       // prologue: sigma_0 ready

        for (int t = 0; t < Tn; ++t) {
            // shadowed: YP stores of step t-1 (drain at barA, hidden)
            if (t > 0) {
                #pragma unroll
                for (int c = 0; c < 4; ++c)
                    if (slotr[c] >= 0) YP[(size_t)(t - 1) * Kk + slotr[c]] = yv64[c];
            }

            // global min from 5 wave partials
            float4 mp4 = *reinterpret_cast<const float4*>(minp);
            float m = fminf(fminf(fminf(mp4.x, mp4.y), fminf(mp4.z, mp4.w)), minp[4]);
            const float m1 = 1.f - m;

            // my 24 sigma values
            float sg[24];
            if (grp) {
                #pragma unroll
                for (int q = 0; q < 6; ++q) {
                    float4 v = *reinterpret_cast<const float4*>(sigma_sh + sgb + 4 * q);
                    sg[4*q] = v.x; sg[4*q+1] = v.y; sg[4*q+2] = v.z; sg[4*q+3] = v.w;
                }
            } else {
                #pragma unroll
                for (int i = 0; i < 24; ++i) sg[i] = 0.f;
            }

            // per-group argmax of pi, sortable keys
            float bs[4], bp[4]; unsigned long long kb[4];
            #pragma unroll
            for (int c = 0; c < 4; ++c) { bs[c]=0.f; bp[c]=0.f; bj[c]=0; kb[c]=0ull; }
            if (grp) {
                #pragma unroll
                for (int c = 0; c < 4; ++c) {
                    float best = -INFINITY, sbv = 0.f, pbv = 0.f; int jb = 0;
                    #pragma unroll
                    for (int j = 0; j < 6; ++j) {
                        int i = 6 * c + j;
                        float pv = (1.f - ps[i]) * (sg[i] + m1);
                        bool bet = pv > best;
                        best = bet ? pv : best;
                        jb  = bet ? j : jb;
                        sbv = bet ? sg[i] : sbv;
                        pbv = bet ? ps[i] : pbv;
                    }
                    unsigned ub = __float_as_uint(best);
                    ub ^= (unsigned)(((int)ub) >> 31) | 0x80000000u;
                    int g = 4 * lane + c;
                    kb[c] = ((unsigned long long)ub << 32) |
                            (unsigned long long)(0xFFFFFFFFu - (unsigned)g);
                    bs[c] = sbv; bp[c] = pbv; bj[c] = jb;
                }
            }

            // ballot quickselect, warm-started from previous theta (exact)
            unsigned long long A = 0ull, B = ~0ull;
            unsigned long long p = thw;
            unsigned long long theta;
            while (true) {
                int cnt = __popcll(__ballot(kb[0] >= p)) + __popcll(__ballot(kb[1] >= p))
                        + __popcll(__ballot(kb[2] >= p)) + __popcll(__ballot(kb[3] >= p));
                if (cnt == Kk) { theta = p; break; }
                if (cnt > Kk) A = p; else B = p;
                unsigned long long m0 = __ballot(kb[0] > A && kb[0] < B);
                unsigned long long m1b = __ballot(kb[1] > A && kb[1] < B);
                unsigned long long m2 = __ballot(kb[2] > A && kb[2] < B);
                unsigned long long m3 = __ballot(kb[3] > A && kb[3] < B);
                int cls; unsigned long long mm;
                if (m0)       { cls = 0; mm = m0; }
                else if (m1b) { cls = 1; mm = m1b; }
                else if (m2)  { cls = 2; mm = m2; }
                else          { cls = 3; mm = m3; }
                int sl = __ffsll(mm) - 1;
                unsigned long long kc = (cls==0)?kb[0]:(cls==1)?kb[1]:(cls==2)?kb[2]:kb[3];
                p = __shfl(kc, sl);
            }
            thw = theta;

            unsigned long long M0 = __ballot(kb[0] >= theta);
            unsigned long long M1 = __ballot(kb[1] >= theta);
            unsigned long long M2 = __ballot(kb[2] >= theta);
            unsigned long long M3 = __ballot(kb[3] >= theta);
            int base1 = __popcll(M0);
            int base2 = base1 + __popcll(M1);
            int base3 = base2 + __popcll(M2);

            #pragma unroll
            for (int c = 0; c < 4; ++c) {
                slotr[c] = -1;
                unsigned long long Mc = (c==0)?M0:(c==1)?M1:(c==2)?M2:M3;
                int bse = (c==0)?0:(c==1)?base1:(c==2)?base2:base3;
                bool s = grp && (kb[c] >= theta);
                float d = 0.f;
                if (s) {
                    int slot = bse + __popcll(Mc & lt);
                    float x = fminf(fmaxf(bs[c], -9.f), 9.f);
                    float e = __expf(2.f * x);
                    float y = 1.f - 2.f / (e + 1.f);
                    float yv = fmaxf(y, 0.f);
                    d = fmaxf(y - 0.5f * bp[c], 0.f);
                    int g = 4 * lane + c;
                    selD[slot] = d;
                    selO[slot] = (6 * g + bj[c]) * TOT;
                    slotr[c] = slot;
                    yv64[c] = ((unsigned long long)(unsigned)g << 32) |
                              (unsigned long long)__float_as_uint(yv);
                }
                dcl[c] = d;
            }

            __syncthreads();                   // bar A: sel published

            // shadowed: psi update (private state, hidden under gather)
            if (grp) {
                #pragma unroll
                for (int c = 0; c < 4; ++c) {
                    #pragma unroll
                    for (int j = 0; j < 6; ++j) {
                        int i = 6 * c + j;
                        float add = (j == bj[c]) ? dcl[c] : 0.f;
                        ps[i] = fmaf(ps[i], 0.5f, add);
                    }
                }
            }

            __syncthreads();                   // bar B: sigma_{t+1} ready
        }

        // final YP stores + epilogue
        #pragma unroll
        for (int c = 0; c < 4; ++c)
            if (slotr[c] >= 0) YP[(size_t)(Tn - 1) * Kk + slotr[c]] = yv64[c];
        if (grp) {
            float a = alphaS;
            float inv2 = (a == 0.f) ? 1.f : (1.f / a);
            #pragma unroll
            for (int i = 0; i < 24; ++i) {
                outTail[cell0 + i]           = ps[i] * inv2;
                outTail[TOT + cell0 + i]     = ps[i];
                outTail[2 * TOT + cell0 + i] = ps[i];
            }
        }
    } else {
        // ================= waves 1-5: gather + alpha + sigma =================
        const int j = tid - 64;                 // 0..319, active j<300
        const bool act = (j < 300);
        const int w = (tid >> 6) - 1;           // 0..4
        const int base = act ? 4 * j : 0;
        const int saddr = act ? ((j / 6) * SP + (4 * j) % 24) : 0;
        const int g0 = base / 6, g1 = (base + 3) / 6;
        const bool f1 = ((base + 1) / 6) != g0;
        const bool f2 = ((base + 2) / 6) != g0;
        const bool f3 = ((base + 3) / 6) != g0;

        float4 cb4 = make_float4(0.f, 0.f, 0.f, 0.f);
        if (act) cb4 = *reinterpret_cast<const float4*>(bb + base);
        float4 uo = make_float4(0.f, 0.f, 0.f, 0.f);
        float alpha = 0.f;

        // sigma_0 = cb + za (u=0, alpha=0 -> inv=1 irrelevant since u=0)
        {
            float za0 = act ? Za[g0] : 0.f;
            float za1 = act ? Za[g1] : 0.f;
            float s0 = cb4.x + za0;
            float s1 = cb4.y + (f1 ? za1 : za0);
            float s2 = cb4.z + (f2 ? za1 : za0);
            float s3 = cb4.w + (f3 ? za1 : za0);
            if (act)
                *reinterpret_cast<float4*>(sigma_sh + saddr) = make_float4(s0,s1,s2,s3);
            float lm = act ? fminf(fminf(s0, s1), fminf(s2, s3)) : INFINITY;
            #pragma unroll
            for (int o = 1; o < 64; o <<= 1) lm = fminf(lm, __shfl_xor(lm, o));
            if (lane == 0) minp[w] = lm;
        }
        __syncthreads();                        // prologue barrier

        for (int t = 0; t < Tn; ++t) {
            uo.x *= 0.5f; uo.y *= 0.5f; uo.z *= 0.5f; uo.w *= 0.5f;

            __syncthreads();                    // bar A: sel ready

            float vD = 0.f; int vO = 0;
            if (lane < 25) { vD = selD[lane]; vO = selO[lane]; }

            // issue za_{t+1} + all 25 column loads (one L2 round trip)
            const int tn = (t + 1 < Tn) ? t + 1 : t;
            float nza0 = act ? Za[(size_t)tn * Mg + g0] : 0.f;
            float nza1 = act ? Za[(size_t)tn * Mg + g1] : 0.f;
            float4 cc[Kk];
            #pragma unroll
            for (int k = 0; k < Kk; ++k) {
                int offk = __builtin_amdgcn_readlane(vO, k);     // SGPR, uniform
                cc[k] = *reinterpret_cast<const float4*>(WbT + offk + base);
            }
            __builtin_amdgcn_sched_barrier(0);  // keep loads clustered

            // alpha recurrence (redundant per wave, hidden under load wait)
            float av = vD;
            #pragma unroll
            for (int o = 1; o < 64; o <<= 1) av += __shfl_xor(av, o);
            alpha = fmaf(alpha, 0.5f, av);
            const float A0  = (alpha == 0.f) ? 1.f : alpha;
            const float inv = 1.f / A0;
            if (w == 0 && lane == 0) alphaS = alpha;

            #pragma unroll
            for (int k = 0; k < Kk; ++k) {
                float dk = __uint_as_float(
                    (unsigned)__builtin_amdgcn_readlane((int)__float_as_uint(vD), k));
                uo.x = fmaf(dk, cc[k].x, uo.x);
                uo.y = fmaf(dk, cc[k].y, uo.y);
                uo.z = fmaf(dk, cc[k].z, uo.z);
                uo.w = fmaf(dk, cc[k].w, uo.w);
            }

            // sigma_{t+1} = u*inv + cb + za_{t+1}; min partial
            float s0 = fmaf(uo.x, inv, cb4.x + nza0);
            float s1 = fmaf(uo.y, inv, cb4.y + (f1 ? nza1 : nza0));
            float s2 = fmaf(uo.z, inv, cb4.z + (f2 ? nza1 : nza0));
            float s3 = fmaf(uo.w, inv, cb4.w + (f3 ? nza1 : nza0));
            if (act)
                *reinterpret_cast<float4*>(sigma_sh + saddr) = make_float4(s0,s1,s2,s3);
            float lm = act ? fminf(fminf(s0, s1), fminf(s2, s3)) : INFINITY;
            #pragma unroll
            for (int o = 1; o < 64; o <<= 1) lm = fminf(lm, __shfl_xor(lm, o));
            if (lane == 0) minp[w] = lm;

            __syncthreads();                    // bar B: sigma published
        }
    }
}

// ------------------------------------------------- preds = bd + sum val * WdT[idx]
__global__ void preds_k(const unsigned long long* __restrict__ YP,
                        const float* __restrict__ WdT, const float* __restrict__ bd,
                        float* __restrict__ out) {
    const int t = blockIdx.x;
    __shared__ float sv[Kk];
    __shared__ int   si[Kk];
    if (threadIdx.x < Kk) {
        unsigned long long v = YP[(size_t)t * Kk + threadIdx.x];
        sv[threadIdx.x] = __uint_as_float((unsigned)v);
        si[threadIdx.x] = (int)(v >> 32);
    }
    __syncthreads();
    for (int d = threadIdx.x; d < Din; d += 256) {
        float acc = bd[d];
        #pragma unroll
        for (int k = 0; k < Kk; ++k)
            acc = fmaf(sv[k], WdT[(size_t)si[k] * Din + d], acc);
        out[(size_t)t * Din + d] = acc;
    }
}

extern "C" void kernel_launch(void* const* d_in, const int* in_sizes, int n_in,
                              void* d_out, int out_size, void* d_ws, size_t ws_size,
                              hipStream_t stream) {
    const float* X  = (const float*)d_in[0];
    const float* Wa = (const float*)d_in[1];
    const float* ba = (const float*)d_in[2];
    const float* Wb = (const float*)d_in[3];
    const float* bb = (const float*)d_in[4];
    const float* Wd = (const float*)d_in[5];
    const float* bd = (const float*)d_in[6];
    float* out = (float*)d_out;

    float* w    = (float*)d_ws;
    float* Za   = w;                                    // 16384*200
    float* WbT  = Za  + (size_t)Tn * Mg;                // 1200*1200
    float* WdT  = WbT + (size_t)TOT * TOT;              // 200*784
    unsigned long long* YP =
        (unsigned long long*)(WdT + (size_t)Mg * Din);  // 16384*25 u64

    dim3 tb(32, 8);
    transpose_k<<<dim3((TOT + 31) / 32, (TOT + 31) / 32), tb, 0, stream>>>(Wb, WbT, TOT, TOT);
    transpose_k<<<dim3((Mg + 31) / 32, (Din + 31) / 32), tb, 0, stream>>>(Wd, WdT, Din, Mg);
    za_k<<<Tn / 16, 256, 0, stream>>>(X, Wa, ba, Za);
    serial_k<<<1, 384, 0, stream>>>(Za, WbT, bb, YP, out + (size_t)Tn * Din);
    preds_k<<<Tn, 256, 0, stream>>>(YP, WdT, bd, out);
}

// Round 12
// 71345.831 us; speedup vs baseline: 2.0580x; 1.0000x over previous
//
#include <hip/hip_runtime.h>
#include <math.h>

#define Tn   16384
#define Mg   200
#define Nc   6
#define TOT  1200
#define Kk   25
#define Din  784
#define SP   28     // padded words per 24-cell block of sigma_sh

// ---------------------------------------------------------------- transpose
__global__ void transpose_k(const float* __restrict__ src, float* __restrict__ dst,
                            int R, int C) {
    __shared__ float tile[32][33];
    int bx = blockIdx.x * 32, by = blockIdx.y * 32;
    int x = bx + threadIdx.x;
    for (int j = 0; j < 32; j += 8) {
        int y = by + threadIdx.y + j;
        if (x < C && y < R) tile[threadIdx.y + j][threadIdx.x] = src[(size_t)y * C + x];
    }
    __syncthreads();
    int x2 = by + threadIdx.x;
    for (int j = 0; j < 32; j += 8) {
        int y2 = bx + threadIdx.y + j;
        if (x2 < R && y2 < C) dst[(size_t)y2 * R + x2] = tile[threadIdx.x][threadIdx.y + j];
    }
}

// ------------------------------------------------- Za = X @ Wa^T + ba  (16384 x 200)
__global__ void za_k(const float* __restrict__ X, const float* __restrict__ Wa,
                     const float* __restrict__ ba, float* __restrict__ Za) {
    __shared__ float xs[16][788];
    const int tid = threadIdx.x;
    const int t0  = blockIdx.x * 16;
    for (int idx = tid; idx < 16 * Din; idx += 256) {
        int tt = idx / Din, kk = idx - tt * Din;
        xs[tt][kk] = X[(size_t)(t0 + tt) * Din + kk];
    }
    __syncthreads();
    const int tq = tid & 15, gq = tid >> 4;
    const float4* xrow = reinterpret_cast<const float4*>(&xs[tq][0]);
    for (int g = gq; g < Mg; g += 16) {
        float acc = ba[g];
        const float4* wrow = reinterpret_cast<const float4*>(Wa + (size_t)g * Din);
        for (int k4 = 0; k4 < Din / 4; ++k4) {
            float4 a = xrow[k4], b = wrow[k4];
            acc = fmaf(a.x, b.x, acc); acc = fmaf(a.y, b.y, acc);
            acc = fmaf(a.z, b.z, acc); acc = fmaf(a.w, b.w, acc);
        }
        Za[(size_t)(t0 + tq) * Mg + g] = acc;
    }
}

// ------------------------------------------------------------- serial recurrence
// Wave0: decision (argmax keys, warm-started ballot quickselect, sel publish).
// psi update + YP stores shadowed after barA/barB. Waves 1-5: u in registers,
// 25-col gather, redundant per-wave alpha recurrence (hidden under load wait),
// sigma_{t+1} + min partials. 2 barriers/step; no VMEM op drains on the
// critical path.
__launch_bounds__(384, 1)
__global__ void serial_k(const float* __restrict__ Za, const float* __restrict__ WbT,
                         const float* __restrict__ bb,
                         unsigned long long* __restrict__ YP,
                         float* __restrict__ outTail) {
    __shared__ alignas(16) float sigma_sh[50 * SP];   // padded, 5.6 KB
    __shared__ alignas(16) float minp[8];
    __shared__ alignas(16) float selD[32];
    __shared__ alignas(16) int   selO[32];
    __shared__ float alphaS;

    const int tid  = threadIdx.x;
    const int lane = tid & 63;

    if (tid < 64) {
        // ================= wave0: decision core =================
        const bool grp = (lane < 50);
        const int sgb  = lane * SP;
        const int cell0 = 24 * lane;
        const unsigned long long lt = (1ull << lane) - 1ull;

        float ps[24];
        #pragma unroll
        for (int i = 0; i < 24; ++i) ps[i] = 0.f;
        unsigned long long thw = 0ull;          // warm pivot across steps
        int slotr[4] = {-1, -1, -1, -1};
        unsigned long long yv64[4] = {0ull, 0ull, 0ull, 0ull};
        int bj[4] = {0, 0, 0, 0};
        float dcl[4] = {0.f, 0.f, 0.f, 0.f};

        __syncthreads();                       // prologue: sigma_0 ready

        for (int t = 0; t < Tn; ++t) {
            // shadowed: YP stores of step t-1 (drain at barA, hidden)
            if (t > 0) {
                #pragma unroll
                for (int c = 0; c < 4; ++c)
                    if (slotr[c] >= 0) YP[(size_t)(t - 1) * Kk + slotr[c]] = yv64[c];
            }

            // global min from 5 wave partials
            float4 mp4 = *reinterpret_cast<const float4*>(minp);
            float m = fminf(fminf(fminf(mp4.x, mp4.y), fminf(mp4.z, mp4.w)), minp[4]);
            const float m1 = 1.f - m;

            // my 24 sigma values
            float sg[24];
            if (grp) {
                #pragma unroll
                for (int q = 0; q < 6; ++q) {
                    float4 v = *reinterpret_cast<const float4*>(sigma_sh + sgb + 4 * q);
                    sg[4*q] = v.x; sg[4*q+1] = v.y; sg[4*q+2] = v.z; sg[4*q+3] = v.w;
                }
            } else {
                #pragma unroll
                for (int i = 0; i < 24; ++i) sg[i] = 0.f;
            }

            // per-group argmax of pi, sortable keys
            float bs[4], bp[4]; unsigned long long kb[4];
            #pragma unroll
            for (int c = 0; c < 4; ++c) { bs[c]=0.f; bp[c]=0.f; bj[c]=0; kb[c]=0ull; }
            if (grp) {
                #pragma unroll
                for (int c = 0; c < 4; ++c) {
                    float best = -INFINITY, sbv = 0.f, pbv = 0.f; int jb = 0;
                    #pragma unroll
                    for (int j = 0; j < 6; ++j) {
                        int i = 6 * c + j;
                        float pv = (1.f - ps[i]) * (sg[i] + m1);
                        bool bet = pv > best;
                        best = bet ? pv : best;
                        jb  = bet ? j : jb;
                        sbv = bet ? sg[i] : sbv;
                        pbv = bet ? ps[i] : pbv;
                    }
                    unsigned ub = __float_as_uint(best);
                    ub ^= (unsigned)(((int)ub) >> 31) | 0x80000000u;
                    int g = 4 * lane + c;
                    kb[c] = ((unsigned long long)ub << 32) |
                            (unsigned long long)(0xFFFFFFFFu - (unsigned)g);
                    bs[c] = sbv; bp[c] = pbv; bj[c] = jb;
                }
            }

            // ballot quickselect, warm-started from previous theta (exact)
            unsigned long long A = 0ull, B = ~0ull;
            unsigned long long p = thw;
            unsigned long long theta;
            while (true) {
                int cnt = __popcll(__ballot(kb[0] >= p)) + __popcll(__ballot(kb[1] >= p))
                        + __popcll(__ballot(kb[2] >= p)) + __popcll(__ballot(kb[3] >= p));
                if (cnt == Kk) { theta = p; break; }
                if (cnt > Kk) A = p; else B = p;
                unsigned long long m0 = __ballot(kb[0] > A && kb[0] < B);
                unsigned long long m1b = __ballot(kb[1] > A && kb[1] < B);
                unsigned long long m2 = __ballot(kb[2] > A && kb[2] < B);
                unsigned long long m3 = __ballot(kb[3] > A && kb[3] < B);
                int cls; unsigned long long mm;
                if (m0)       { cls = 0; mm = m0; }
                else if (m1b) { cls = 1; mm = m1b; }
                else if (m2)  { cls = 2; mm = m2; }
                else          { cls = 3; mm = m3; }
                int sl = __ffsll(mm) - 1;
                unsigned long long kc = (cls==0)?kb[0]:(cls==1)?kb[1]:(cls==2)?kb[2]:kb[3];
                p = __shfl(kc, sl);
            }
            thw = theta;

            unsigned long long M0 = __ballot(kb[0] >= theta);
            unsigned long long M1 = __ballot(kb[1] >= theta);
            unsigned long long M2 = __ballot(kb[2] >= theta);
            unsigned long long M3 = __ballot(kb[3] >= theta);
            int base1 = __popcll(M0);
            int base2 = base1 + __popcll(M1);
            int base3 = base2 + __popcll(M2);

            #pragma unroll
            for (int c = 0; c < 4; ++c) {
                slotr[c] = -1;
                unsigned long long Mc = (c==0)?M0:(c==1)?M1:(c==2)?M2:M3;
                int bse = (c==0)?0:(c==1)?base1:(c==2)?base2:base3;
                bool s = grp && (kb[c] >= theta);
                float d = 0.f;
                if (s) {
                    int slot = bse + __popcll(Mc & lt);
                    float x = fminf(fmaxf(bs[c], -9.f), 9.f);
                    float e = __expf(2.f * x);
                    float y = 1.f - 2.f / (e + 1.f);
                    float yv = fmaxf(y, 0.f);
                    d = fmaxf(y - 0.5f * bp[c], 0.f);
                    int g = 4 * lane + c;
                    selD[slot] = d;
                    selO[slot] = (6 * g + bj[c]) * TOT;
                    slotr[c] = slot;
                    yv64[c] = ((unsigned long long)(unsigned)g << 32) |
                              (unsigned long long)__float_as_uint(yv);
                }
                dcl[c] = d;
            }

            __syncthreads();                   // bar A: sel published

            // shadowed: psi update (private state, hidden under gather)
            if (grp) {
                #pragma unroll
                for (int c = 0; c < 4; ++c) {
                    #pragma unroll
                    for (int j = 0; j < 6; ++j) {
                        int i = 6 * c + j;
                        float add = (j == bj[c]) ? dcl[c] : 0.f;
                        ps[i] = fmaf(ps[i], 0.5f, add);
                    }
                }
            }

            __syncthreads();                   // bar B: sigma_{t+1} ready
        }

        // final YP stores + epilogue
        #pragma unroll
        for (int c = 0; c < 4; ++c)
            if (slotr[c] >= 0) YP[(size_t)(Tn - 1) * Kk + slotr[c]] = yv64[c];
        if (grp) {
            float a = alphaS;
            float inv2 = (a == 0.f) ? 1.f : (1.f / a);
            #pragma unroll
            for (int i = 0; i < 24; ++i) {
                outTail[cell0 + i]           = ps[i] * inv2;
                outTail[TOT + cell0 + i]     = ps[i];
                outTail[2 * TOT + cell0 + i] = ps[i];
            }
        }
    } else {
        // ================= waves 1-5: gather + alpha + sigma =================
        const int j = tid - 64;                 // 0..319, active j<300
        const bool act = (j < 300);
        const int w = (tid >> 6) - 1;           // 0..4
        const int base = act ? 4 * j : 0;
        const int saddr = act ? ((j / 6) * SP + (4 * j) % 24) : 0;
        const int g0 = base / 6, g1 = (base + 3) / 6;
        const bool f1 = ((base + 1) / 6) != g0;
        const bool f2 = ((base + 2) / 6) != g0;
        const bool f3 = ((base + 3) / 6) != g0;

        float4 cb4 = make_float4(0.f, 0.f, 0.f, 0.f);
        if (act) cb4 = *reinterpret_cast<const float4*>(bb + base);
        float4 uo = make_float4(0.f, 0.f, 0.f, 0.f);
        float alpha = 0.f;

        // sigma_0 = cb + za (u=0, alpha=0 -> inv=1 irrelevant since u=0)
        {
            float za0 = act ? Za[g0] : 0.f;
            float za1 = act ? Za[g1] : 0.f;
            float s0 = cb4.x + za0;
            float s1 = cb4.y + (f1 ? za1 : za0);
            float s2 = cb4.z + (f2 ? za1 : za0);
            float s3 = cb4.w + (f3 ? za1 : za0);
            if (act)
                *reinterpret_cast<float4*>(sigma_sh + saddr) = make_float4(s0,s1,s2,s3);
            float lm = act ? fminf(fminf(s0, s1), fminf(s2, s3)) : INFINITY;
            #pragma unroll
            for (int o = 1; o < 64; o <<= 1) lm = fminf(lm, __shfl_xor(lm, o));
            if (lane == 0) minp[w] = lm;
        }
        __syncthreads();                        // prologue barrier

        for (int t = 0; t < Tn; ++t) {
            uo.x *= 0.5f; uo.y *= 0.5f; uo.z *= 0.5f; uo.w *= 0.5f;

            __syncthreads();                    // bar A: sel ready

            float vD = 0.f; int vO = 0;
            if (lane < 25) { vD = selD[lane]; vO = selO[lane]; }

            // issue za_{t+1} + all 25 column loads (one L2 round trip)
            const int tn = (t + 1 < Tn) ? t + 1 : t;
            float nza0 = act ? Za[(size_t)tn * Mg + g0] : 0.f;
            float nza1 = act ? Za[(size_t)tn * Mg + g1] : 0.f;
            float4 cc[Kk];
            #pragma unroll
            for (int k = 0; k < Kk; ++k) {
                int offk = __builtin_amdgcn_readlane(vO, k);     // SGPR, uniform
                cc[k] = *reinterpret_cast<const float4*>(WbT + offk + base);
            }
            __builtin_amdgcn_sched_barrier(0);  // keep loads clustered

            // alpha recurrence (redundant per wave, hidden under load wait)
            float av = vD;
            #pragma unroll
            for (int o = 1; o < 64; o <<= 1) av += __shfl_xor(av, o);
            alpha = fmaf(alpha, 0.5f, av);
            const float A0  = (alpha == 0.f) ? 1.f : alpha;
            const float inv = 1.f / A0;
            if (w == 0 && lane == 0) alphaS = alpha;

            #pragma unroll
            for (int k = 0; k < Kk; ++k) {
                float dk = __uint_as_float(
                    (unsigned)__builtin_amdgcn_readlane((int)__float_as_uint(vD), k));
                uo.x = fmaf(dk, cc[k].x, uo.x);
                uo.y = fmaf(dk, cc[k].y, uo.y);
                uo.z = fmaf(dk, cc[k].z, uo.z);
                uo.w = fmaf(dk, cc[k].w, uo.w);
            }

            // sigma_{t+1} = u*inv + cb + za_{t+1}; min partial
            float s0 = fmaf(uo.x, inv, cb4.x + nza0);
            float s1 = fmaf(uo.y, inv, cb4.y + (f1 ? nza1 : nza0));
            float s2 = fmaf(uo.z, inv, cb4.z + (f2 ? nza1 : nza0));
            float s3 = fmaf(uo.w, inv, cb4.w + (f3 ? nza1 : nza0));
            if (act)
                *reinterpret_cast<float4*>(sigma_sh + saddr) = make_float4(s0,s1,s2,s3);
            float lm = act ? fminf(fminf(s0, s1), fminf(s2, s3)) : INFINITY;
            #pragma unroll
            for (int o = 1; o < 64; o <<= 1) lm = fminf(lm, __shfl_xor(lm, o));
            if (lane == 0) minp[w] = lm;

            __syncthreads();                    // bar B: sigma published
        }
    }
}

// ------------------------------------------------- preds = bd + sum val * WdT[idx]
__global__ void preds_k(const unsigned long long* __restrict__ YP,
                        const float* __restrict__ WdT, const float* __restrict__ bd,
                        float* __restrict__ out) {
    const int t = blockIdx.x;
    __shared__ float sv[Kk];
    __shared__ int   si[Kk];
    if (threadIdx.x < Kk) {
        unsigned long long v = YP[(size_t)t * Kk + threadIdx.x];
        sv[threadIdx.x] = __uint_as_float((unsigned)v);
        si[threadIdx.x] = (int)(v >> 32);
    }
    __syncthreads();
    for (int d = threadIdx.x; d < Din; d += 256) {
        float acc = bd[d];
        #pragma unroll
        for (int k = 0; k < Kk; ++k)
            acc = fmaf(sv[k], WdT[(size_t)si[k] * Din + d], acc);
        out[(size_t)t * Din + d] = acc;
    }
}

extern "C" void kernel_launch(void* const* d_in, const int* in_sizes, int n_in,
                              void* d_out, int out_size, void* d_ws, size_t ws_size,
                              hipStream_t stream) {
    const float* X  = (const float*)d_in[0];
    const float* Wa = (const float*)d_in[1];
    const float* ba = (const float*)d_in[2];
    const float* Wb = (const float*)d_in[3];
    const float* bb = (const float*)d_in[4];
    const float* Wd = (const float*)d_in[5];
    const float* bd = (const float*)d_in[6];
    float* out = (float*)d_out;

    float* w    = (float*)d_ws;
    float* Za   = w;                                    // 16384*200
    float* WbT  = Za  + (size_t)Tn * Mg;                // 1200*1200
    float* WdT  = WbT + (size_t)TOT * TOT;              // 200*784
    unsigned long long* YP =
        (unsigned long long*)(WdT + (size_t)Mg * Din);  // 16384*25 u64

    dim3 tb(32, 8);
    transpose_k<<<dim3((TOT + 31) / 32, (TOT + 31) / 32), tb, 0, stream>>>(Wb, WbT, TOT, TOT);
    transpose_k<<<dim3((Mg + 31) / 32, (Din + 31) / 32), tb, 0, stream>>>(Wd, WdT, Din, Mg);
    za_k<<<Tn / 16, 256, 0, stream>>>(X, Wa, ba, Za);
    serial_k<<<1, 384, 0, stream>>>(Za, WbT, bb, YP, out + (size_t)Tn * Din);
    preds_k<<<Tn, 256, 0, stream>>>(YP, WdT, bd, out);
}